// Round 13
// baseline (53.378 us; speedup 1.0000x reference)
//
#include <hip/hip_runtime.h>

// L2-distance causal attention with zero-KV sink.
// B=2, H=16, N=2048, D=64. fp32 in/out, bf16 MFMA internally.
//
// Round 12 = Round 11 + V moved out of LDS (fragment-major global reads).
//   - No online-softmax machinery (sink pins max; bias folded into V' and tb).
//   - K: LDS, 3 buffers (24 KB), 2-deep staging, ONE raw s_barrier +
//     counted s_waitcnt vmcnt(2) per tile (K(t+2) stays in flight).
//   - V': fragment-major per-tile image (16B per (frag,lane) in exact wave
//     read order) -> 8 coalesced global_load_dwordx4 per tile, per-wave
//     private, certified by the same vmcnt(2). No barrier coupling, and the
//     4 waves' identical reads hit L1.
//   - tb (2^bias) loaded to regs per tile, certified by the same vmcnt(2).
//   - 24 KB LDS + ~110 VGPR -> 4 blocks/CU = 16 waves/CU, 1024 blocks all
//     resident. Grid (32,32), y reversed (heavy q-blocks first).

#define NQ 2048
#define DH 64
#define NT 32   // KV tiles per sequence (2048/64)

typedef float f32x4 __attribute__((ext_vector_type(4)));
typedef __bf16 bf16x8 __attribute__((ext_vector_type(8)));
typedef unsigned short u16x8 __attribute__((ext_vector_type(8)));

union B8 { u16x8 u; bf16x8 b; };

__device__ __forceinline__ unsigned short f2b(float f) {
  unsigned int x = __builtin_bit_cast(unsigned int, f);
  unsigned int r = x + 0x7fffu + ((x >> 16) & 1u);   // RNE to bf16
  return (unsigned short)(r >> 16);
}
__device__ __forceinline__ float b2f(unsigned short u) {
  unsigned int t = ((unsigned int)u) << 16;
  return __builtin_bit_cast(float, t);
}

// K-slot permutation: slot s (bits c1 c0 g1 g0 r1 r0) holds key (c1 g1 g0 c0 r1 r0).
// Makes QK^T's C-layout scores be exactly the PV B-fragment values (no exchange).
__device__ __forceinline__ int kslot(int a) {
  return (a & 0x23) | ((a & 0x04) << 2) | ((a & 0x18) >> 1);
}

__device__ __forceinline__ void gl_lds16(const void* g, void* l) {
  __builtin_amdgcn_global_load_lds(
      (const __attribute__((address_space(1))) unsigned int*)g,
      (__attribute__((address_space(3))) unsigned int*)l, 16, 0, 0);
}

constexpr float QS = 0.3551784733906239f;   // 2*log2(e)/sqrt(66)
constexpr float BS = 0.17758923669531197f;  // log2(e)/sqrt(66)

// ---------------- kernel 1: build per-tile images ----------------
__global__ __launch_bounds__(256) void build_ws(
    const float* __restrict__ k, const float* __restrict__ v,
    unsigned short* __restrict__ wsK, unsigned short* __restrict__ wsV,
    float* __restrict__ wsB)
{
  const int bh = blockIdx.x;          // 0..31
  const int t  = blockIdx.y;          // 0..31
  const int tid  = threadIdx.x;
  const int wid  = tid >> 6;
  const int lane = tid & 63;
  const int g    = lane >> 4;
  const int qi   = lane & 15;
  const size_t bhN = (size_t)bh * NQ;
  const int tile64 = t * 64;
  const size_t tileId = (size_t)bh * NT + t;
  unsigned short* Kt  = wsK + tileId * 4096;
  unsigned short* VtF = wsV + tileId * 4096;   // fragment-major V' image
  float*          Bt  = wsB + tileId * 64;

  __shared__ float sTb[64];                           // 2^{b_j} by KEY index
  __shared__ __align__(16) unsigned short sV[4096];   // staging for phase 2

  // ---- phase 1a: K image (+ tb), slot-permuted, XOR-swizzled ----
#pragma unroll
  for (int i = 0; i < 4; i++) {
    int f  = i * 256 + tid;
    int kg = f >> 4, d4 = f & 15;
    int slot = kslot(kg);
    const float4* kp = (const float4*)(k + (bhN + tile64 + kg) * DH);
    float4 kk = kp[d4];
    unsigned short h0 = f2b(kk.x), h1 = f2b(kk.y), h2 = f2b(kk.z), h3 = f2b(kk.w);
    float a0 = b2f(h0), a1 = b2f(h1), a2 = b2f(h2), a3 = b2f(h3);
    float ss = a0*a0 + a1*a1 + a2*a2 + a3*a3;     // |k_bf|^2 partial
    ss += __shfl_xor(ss, 1, 64);
    ss += __shfl_xor(ss, 2, 64);
    ss += __shfl_xor(ss, 4, 64);
    ss += __shfl_xor(ss, 8, 64);
    if (d4 == 0) {
      float tb = __builtin_amdgcn_exp2f(-BS * ss);  // 2^{bias}
      Bt[slot] = tb;       // slot-permuted image for the attend kernel
      sTb[kg]  = tb;       // key-indexed for the V pass below
    }
    unsigned int w0 = (unsigned int)h0 | ((unsigned int)h1 << 16);
    unsigned int w1 = (unsigned int)h2 | ((unsigned int)h3 << 16);
    int idx = slot * 64 + ((d4 * 4) ^ ((slot & 7) << 3));
    uint2 wv; wv.x = w0; wv.y = w1;
    *(uint2*)&Kt[idx] = wv;
  }
  __syncthreads();

  // ---- phase 1b: V'^T image into LDS (XOR-swizzled, scaled by 2^{b_j}) ----
#pragma unroll
  for (int jj = 0; jj < 4; jj++) {
    int kgb = jj * 16 + wid * 4;
    const float* vp = v + (bhN + tile64 + kgb) * DH + lane;
    float x0 = vp[0] * sTb[kgb + 0];
    float x1 = vp[DH] * sTb[kgb + 1];
    float x2 = vp[2 * DH] * sTb[kgb + 2];
    float x3 = vp[3 * DH] * sTb[kgb + 3];
    unsigned int w0 = (unsigned int)f2b(x0) | ((unsigned int)f2b(x1) << 16);
    unsigned int w1 = (unsigned int)f2b(x2) | ((unsigned int)f2b(x3) << 16);
    int idx = lane * 64 + (kgb ^ ((lane & 7) << 3));
    uint2 wv; wv.x = w0; wv.y = w1;
    *(uint2*)&sV[idx] = wv;
  }
  __syncthreads();

  // ---- phase 2: linearize V fragment-major (exact wave read order) ----
  // V frag f=(db*2+ks): lane needs sV[(db*16+qi)*64 + ((ks*32+g*8)^((qi&7)<<3))]
#pragma unroll
  for (int f4 = 0; f4 < 2; f4++) {
    int f  = wid * 2 + f4;           // 0..7
    int cc = f >> 1, ks = f & 1;
    int sw = ((ks * 32 + g * 8) ^ ((qi & 7) << 3));
    bf16x8 vv = *(const bf16x8*)&sV[(cc * 16 + qi) * 64 + sw];
    *(bf16x8*)&VtF[(f * 64 + lane) * 8] = vv;
  }
}

// ---------------- kernel 2: K-in-LDS, V-from-global flash attention ----------------
__global__ __launch_bounds__(256) void attend_l2_flash(
    const float* __restrict__ q,
    const unsigned short* __restrict__ wsK,
    const unsigned short* __restrict__ wsV,
    const float* __restrict__ wsB,
    float* __restrict__ out)
{
  const int bh   = blockIdx.x;
  const int qt   = (gridDim.y - 1) - blockIdx.y;   // heavy tiles dispatch first
  const int qbase = qt * 64;
  const int tid  = threadIdx.x;
  const int wid  = tid >> 6;
  const int lane = tid & 63;
  const int g    = lane >> 4;
  const int qi   = lane & 15;
  const int qg   = qbase + wid * 16 + qi;          // this lane's query row
  const size_t bhN = (size_t)bh * NQ;

  __shared__ __align__(16) unsigned short sK[3][4096];   // 3-deep K rotation

  // ---- Q fragments (single bf16 pass), hoisted ----
  const float* qrow = q + (bhN + qg) * DH;
  bf16x8 q8[2];
#pragma unroll
  for (int ks = 0; ks < 2; ks++) {
    B8 th;
#pragma unroll
    for (int j = 0; j < 8; j++)
      th.u[j] = f2b(qrow[ks * 32 + g * 8 + j] * QS);
    q8[ks] = th.b;
  }

  f32x4 oacc[4] = { {0,0,0,0}, {0,0,0,0}, {0,0,0,0}, {0,0,0,0} };
  f32x4 l4 = {0, 0, 0, 0};        // packed partial denominator

  const int ntiles = qt + 1;
  const size_t tbase = (size_t)bh * NT;
  const char*  Vws = (const char*)(wsV + tbase * 4096);
  const float* TB  = wsB + tbase * 64;

  // stage K-tile t into LDS buffer: 2 gl_lds16 per thread (8 KB linear DMA)
  auto STAGE_K = [&](unsigned short* bK, int t) {
    const char* Kt = (const char*)(wsK + (tbase + t) * 4096);
#pragma unroll
    for (int c = 0; c < 2; c++)
      gl_lds16(Kt + c * 4096 + tid * 16, (char*)bK + c * 4096 + tid * 16);
  };

  unsigned short *kA = sK[0], *kB = sK[1], *kC = sK[2];

  // prologue: K0 | K1 -> vmcnt(2) leaves K1 in flight, K0 certified
  STAGE_K(kA, 0);
  __builtin_amdgcn_sched_barrier(0);
  STAGE_K(kB, (ntiles > 1) ? 1 : 0);
  __builtin_amdgcn_sched_barrier(0);
  asm volatile("s_waitcnt vmcnt(2)" ::: "memory");
  __builtin_amdgcn_s_barrier();

  for (int t = 0; t < ntiles; t++) {
    // ---- V'(t) fragments -> regs (8 VMEM, per-wave private, L1-shared) ----
    const char* Vt = Vws + (size_t)t * 8192;
    bf16x8 vf[8];
#pragma unroll
    for (int f = 0; f < 8; f++)
      vf[f] = *(const bf16x8*)(Vt + f * 1024 + lane * 16);
    __builtin_amdgcn_sched_barrier(0);

    // ---- tb(t) -> regs (4 VMEM) ----
    const float* bp = TB + t * 64 + 4 * g;
    f32x4 tb[4];
#pragma unroll
    for (int c = 0; c < 4; c++) tb[c] = *(const f32x4*)(bp + 16 * c);
    __builtin_amdgcn_sched_barrier(0);

    // ---- STAGE K(t+2) (2 VMEM, LAST issued -> stays in flight) ----
    STAGE_K(kC, (t + 2 < ntiles) ? (t + 2) : (ntiles - 1));
    __builtin_amdgcn_sched_barrier(0);

    // ---- QK^T from kA, swapped: S^T = K . Q^T (8 MFMA) ----
    f32x4 sc[4] = { {0,0,0,0}, {0,0,0,0}, {0,0,0,0}, {0,0,0,0} };
#pragma unroll
    for (int c = 0; c < 4; c++) {
#pragma unroll
      for (int ks = 0; ks < 2; ks++) {
        int idx = (16 * c + qi) * 64 + ((ks * 32 + g * 8) ^ ((qi & 7) << 3));
        bf16x8 ak = *(const bf16x8*)&kA[idx];
        sc[c] = __builtin_amdgcn_mfma_f32_16x16x32_bf16(ak, q8[ks], sc[c], 0, 0, 0);
      }
    }
    __builtin_amdgcn_sched_barrier(0);

    // ---- counted wait: V(t), tb(t), K(t+1) certified; K(t+2) in flight ----
    asm volatile("s_waitcnt vmcnt(2)" ::: "memory");
    __builtin_amdgcn_sched_barrier(0);

    // ---- causal mask on diag tile (masked -> exp2 gives exactly 0) ----
    if (t == ntiles - 1) {
      const int tile64 = t * 64;
#pragma unroll
      for (int c = 0; c < 4; c++)
#pragma unroll
        for (int r = 0; r < 4; r++) {
          int key = tile64 + 32 * (c >> 1) + 8 * g + 4 * (c & 1) + r; // pi(slot)
          if (key > qg) sc[c][r] = -1e30f;
        }
    }

    // ---- weights: p = exp2(s_raw); l += p * tb (no max, no rescale) ----
#pragma unroll
    for (int c = 0; c < 4; c++) {
#pragma unroll
      for (int r = 0; r < 4; r++) sc[c][r] = __builtin_amdgcn_exp2f(sc[c][r]);
#pragma unroll
      for (int r = 0; r < 4; r++) l4[r] = __builtin_fmaf(sc[c][r], tb[c][r], l4[r]);
    }

    // ---- P repack (local by slot-permutation construction) ----
    B8 t0, t1;
#pragma unroll
    for (int j = 0; j < 8; j++) {
      t0.b[j] = (__bf16)sc[(j >> 2)][j & 3];
      t1.b[j] = (__bf16)sc[2 + (j >> 2)][j & 3];
    }

    // ---- PV from vf registers: O^T += V'^T . P^T ----
#pragma unroll
    for (int db = 0; db < 4; db++) {
#pragma unroll
      for (int ks = 0; ks < 2; ks++) {
        oacc[db] = __builtin_amdgcn_mfma_f32_16x16x32_bf16(vf[db * 2 + ks],
                                                           (ks ? t1.b : t0.b),
                                                           oacc[db], 0, 0, 0);
      }
    }

    __builtin_amdgcn_s_barrier();   // all waves done reading kA; rotate
    unsigned short* tk = kA; kA = kB; kB = kC; kC = tk;
  }

  // ---- epilogue: denom = sum(p*tb) + sink weight 1.0 ----
  float lt = (l4[0] + l4[1]) + (l4[2] + l4[3]);
  lt += __shfl_xor(lt, 16, 64);
  lt += __shfl_xor(lt, 32, 64);
  float denom = lt + 1.0f;
  float inv = 1.0f / denom;
  float* op = out + (bhN + qg) * DH;
#pragma unroll
  for (int db = 0; db < 4; db++) {
    float4 o;
    o.x = oacc[db][0] * inv;
    o.y = oacc[db][1] * inv;
    o.z = oacc[db][2] * inv;
    o.w = oacc[db][3] * inv;
    *(float4*)(op + db * 16 + 4 * g) = o;
  }
}

extern "C" void kernel_launch(void* const* d_in, const int* in_sizes, int n_in,
                              void* d_out, int out_size, void* d_ws, size_t ws_size,
                              hipStream_t stream) {
  (void)in_sizes; (void)n_in; (void)out_size; (void)ws_size;
  const float* q = (const float*)d_in[0];
  const float* k = (const float*)d_in[1];
  const float* v = (const float*)d_in[2];
  float* out = (float*)d_out;

  // ws layout: K images 8 MiB | V images 8 MiB | tb 256 KiB
  char* ws = (char*)d_ws;
  unsigned short* wsK = (unsigned short*)ws;
  unsigned short* wsV = (unsigned short*)(ws + (8u << 20));
  float*          wsB = (float*)(ws + (16u << 20));

  build_ws<<<dim3(32, NT), dim3(256), 0, stream>>>(k, v, wsK, wsV, wsB);
  attend_l2_flash<<<dim3(32, NT), dim3(256), 0, stream>>>(q, wsK, wsV, wsB, out);
}